// Round 2
// baseline (266.417 us; speedup 1.0000x reference)
//
#include <hip/hip_runtime.h>
#include <math.h>

#define B 4096
#define N 10000
#define D 256
#define ALPHA 0.2f
#define RANK_SEGS 8
#define CS 16           // chunk size along sorted order
#define G (N / CS)      // 625 chunks exactly (625*16 == 10000)

// --- 1) s_b = P[b]·Wp (b<B), t_n = V[n]·Wn (n<N). One 64-thread wave per row.
__global__ __launch_bounds__(64) void k_dot_scores(
    const float* __restrict__ P, const float* __restrict__ V, const float* __restrict__ K,
    float* __restrict__ t, float* __restrict__ s) {
  int j = blockIdx.x;
  int lane = threadIdx.x;
  const float* row; const float* w; float* outp; int oi;
  if (j < N) { row = V + (size_t)j * D; w = K + D; outp = t; oi = j; }
  else       { row = P + (size_t)(j - N) * D; w = K; outp = s; oi = j - N; }
  float4 r  = ((const float4*)row)[lane];
  float4 kk = ((const float4*)w)[lane];
  float acc = r.x * kk.x + r.y * kk.y + r.z * kk.z + r.w * kk.w;
  #pragma unroll
  for (int off = 32; off > 0; off >>= 1) acc += __shfl_down(acc, off, 64);
  if (lane == 0) outp[oi] = acc;
}

// --- 2) rank_n = #{m : t_m < t_n or (t_m==t_n and m<n)} — counting-sort rank.
__global__ __launch_bounds__(256) void k_rank_partial(
    const float* __restrict__ t, int* __restrict__ rank) {
  __shared__ float sm[256];
  int n = blockIdx.x * 256 + threadIdx.x;
  float tn = (n < N) ? t[n] : 0.f;
  int seglen = (N + RANK_SEGS - 1) / RANK_SEGS;
  int m0 = blockIdx.y * seglen;
  int m1 = min(N, m0 + seglen);
  int r = 0;
  for (int k0 = m0; k0 < m1; k0 += 256) {
    int m = k0 + threadIdx.x;
    sm[threadIdx.x] = (m < m1) ? t[m] : 0.f;
    __syncthreads();
    int lim = min(256, m1 - k0);
    for (int j = 0; j < lim; ++j) {
      float tm = sm[j];
      int mm = k0 + j;
      r += (tm < tn || (tm == tn && mm < n)) ? 1 : 0;
    }
    __syncthreads();
  }
  if (n < N && r) atomicAdd(&rank[n], r);
}

// --- 3) scatter into sorted order; precompute exp factors.
__global__ __launch_bounds__(256) void k_scatter(
    const float* __restrict__ t, const int* __restrict__ rank,
    float* __restrict__ tsort, float* __restrict__ eA, float* __restrict__ eC,
    int* __restrict__ idxs) {
  int n = blockIdx.x * 256 + threadIdx.x;
  if (n < N) {
    int r = rank[n];
    float tn = t[n];
    tsort[r] = tn;
    eA[r] = __expf(tn);
    eC[r] = __expf(ALPHA * tn);
    idxs[r] = n;
  }
}

// --- 4a) per-chunk sums: SA[g][d] = sum_{i in chunk g} eA[i]*V[idxs[i]][d]
// (SC with eC). Scalar chunk sums sa0/sc0 for the softmax denominator.
// Fully unrolled j-loop: all idx/row loads issue early; coalesced row I/O.
__global__ __launch_bounds__(256) void k_chunk_sums(
    const float* __restrict__ eA, const float* __restrict__ eC,
    const int* __restrict__ idxs, const float* __restrict__ V,
    float* __restrict__ SA, float* __restrict__ SC,
    float* __restrict__ sa0, float* __restrict__ sc0) {
  int g = blockIdx.x, d = threadIdx.x;
  int base = g * CS;
  float accA = 0.f, accC = 0.f, sa = 0.f, sc = 0.f;
  #pragma unroll
  for (int j = 0; j < CS; ++j) {
    int i = base + j;
    float ea = eA[i], ec = eC[i];
    float v = V[(size_t)idxs[i] * D + d];
    accA += ea * v; accC += ec * v;
    sa += ea; sc += ec;
  }
  SA[(size_t)g * D + d] = accA;
  SC[(size_t)g * D + d] = accC;
  if (d == 0) { sa0[g] = sa; sc0[g] = sc; }
}

// --- 4b) exclusive scan over chunks (G=625 rows). One block; thread d owns
// column d; coalesced row read + row write per iteration; dep chain = 1 add.
__global__ __launch_bounds__(256) void k_scan_chunks(
    const float* __restrict__ SA, const float* __restrict__ SC,
    const float* __restrict__ sa0, const float* __restrict__ sc0,
    float* __restrict__ PAg, float* __restrict__ PCg,
    float* __restrict__ Pa0, float* __restrict__ Pc0) {
  int d = threadIdx.x;
  float aA = 0.f, aC = 0.f, a0 = 0.f, c0 = 0.f;
  for (int g = 0; g < G; ++g) {
    PAg[(size_t)g * D + d] = aA;
    PCg[(size_t)g * D + d] = aC;
    aA += SA[(size_t)g * D + d];
    aC += SC[(size_t)g * D + d];
    if (d == 0) { Pa0[g] = a0; Pc0[g] = c0; a0 += sa0[g]; c0 += sc0[g]; }
  }
  PAg[(size_t)G * D + d] = aA;
  PCg[(size_t)G * D + d] = aC;
  if (d == 0) { Pa0[G] = a0; Pc0[G] = c0; }
}

// --- 5) per-patient: binary search k_b, chunk-prefix + <=15-row remainder,
// fused epilogue.
__global__ __launch_bounds__(256) void k_finalize(
    const float* __restrict__ P, const float* __restrict__ s,
    const float* __restrict__ tsort,
    const float* __restrict__ eA, const float* __restrict__ eC,
    const int* __restrict__ idxs, const float* __restrict__ V,
    const float* __restrict__ PAg, const float* __restrict__ PCg,
    const float* __restrict__ Pa0, const float* __restrict__ Pc0,
    float* __restrict__ out) {
  int b = blockIdx.x, d = threadIdx.x;
  float sb = s[b];
  float key = -sb;
  int lo = 0, hi = N;   // lower_bound: first idx with tsort[idx] >= key
  while (lo < hi) {
    int mid = (lo + hi) >> 1;
    if (tsort[mid] < key) lo = mid + 1; else hi = mid;
  }
  int k = lo;           // elements [0,k) take the alpha branch; [k,N) the + branch
  int g = k >> 4;       // chunk index; k==N -> g==G (total row, remainder empty)
  float prefA = PAg[(size_t)g * D + d];
  float prefC = PCg[(size_t)g * D + d];
  float pa = Pa0[g], pc = Pc0[g];
  for (int i = g << 4; i < k; ++i) {
    float ea = eA[i], ec = eC[i];
    float v = V[(size_t)idxs[i] * D + d];
    prefA += ea * v; prefC += ec * v;
    pa += ea; pc += ec;
  }
  float totA = PAg[(size_t)G * D + d];
  float ta0 = Pa0[G];
  float ea = __expf(sb), ec = __expf(ALPHA * sb);
  float l = ea * (ta0 - pa) + ec * pc;
  float agg = (ea * (totA - prefA) + ec * prefC) / l;
  out[(size_t)b * D + d] = P[(size_t)b * D + d] + agg;
}

extern "C" void kernel_launch(void* const* d_in, const int* in_sizes, int n_in,
                              void* d_out, int out_size, void* d_ws, size_t ws_size,
                              hipStream_t stream) {
  const float* P = (const float*)d_in[0];   // (B, D)
  const float* V = (const float*)d_in[1];   // (N, D)
  const float* K = (const float*)d_in[2];   // (2D, 1)
  float* out = (float*)d_out;

  char* w = (char*)d_ws;
  float* t     = (float*)w; w += sizeof(float) * N;
  float* s     = (float*)w; w += sizeof(float) * B;
  float* tsort = (float*)w; w += sizeof(float) * N;
  float* eA    = (float*)w; w += sizeof(float) * N;
  float* eC    = (float*)w; w += sizeof(float) * N;
  int*   idxs  = (int*)w;   w += sizeof(int) * N;
  int*   rank  = (int*)w;   w += sizeof(int) * N;
  float* SA    = (float*)w; w += sizeof(float) * (size_t)G * D;
  float* SC    = (float*)w; w += sizeof(float) * (size_t)G * D;
  float* PAg   = (float*)w; w += sizeof(float) * (size_t)(G + 1) * D;
  float* PCg   = (float*)w; w += sizeof(float) * (size_t)(G + 1) * D;
  float* sa0   = (float*)w; w += sizeof(float) * G;
  float* sc0   = (float*)w; w += sizeof(float) * G;
  float* Pa0   = (float*)w; w += sizeof(float) * (G + 1);
  float* Pc0   = (float*)w; w += sizeof(float) * (G + 1);
  // total ~2.9 MB of ws

  hipMemsetAsync(rank, 0, sizeof(int) * N, stream);
  k_dot_scores<<<N + B, 64, 0, stream>>>(P, V, K, t, s);
  dim3 rg((N + 255) / 256, RANK_SEGS);
  k_rank_partial<<<rg, 256, 0, stream>>>(t, rank);
  k_scatter<<<(N + 255) / 256, 256, 0, stream>>>(t, rank, tsort, eA, eC, idxs);
  k_chunk_sums<<<G, 256, 0, stream>>>(eA, eC, idxs, V, SA, SC, sa0, sc0);
  k_scan_chunks<<<1, 256, 0, stream>>>(SA, SC, sa0, sc0, PAg, PCg, Pa0, Pc0);
  k_finalize<<<B, 256, 0, stream>>>(P, s, tsort, eA, eC, idxs, V,
                                    PAg, PCg, Pa0, Pc0, out);
}

// Round 3
// 145.773 us; speedup vs baseline: 1.8276x; 1.8276x over previous
//
#include <hip/hip_runtime.h>
#include <math.h>

#define B 4096
#define N 10000
#define D 256
#define ALPHA 0.2f
#define RANK_SEGS 8
#define CS 16               // rows per chunk
#define G (N / CS)          // 625 chunks (exact)
#define SCHUNK 25           // chunks per superchunk
#define NSUPER (G / SCHUNK) // 25 superchunks (exact)

// --- 1) s_b = P[b]·Wp, t_n = V[n]·Wn. 4 rows per 256-block, one wave per row.
__global__ __launch_bounds__(256) void k_dot_scores(
    const float* __restrict__ P, const float* __restrict__ V, const float* __restrict__ K,
    float* __restrict__ t, float* __restrict__ s) {
  int j = blockIdx.x * 4 + (threadIdx.x >> 6);
  int lane = threadIdx.x & 63;
  if (j >= N + B) return;
  const float* row; const float* w; float* outp; int oi;
  if (j < N) { row = V + (size_t)j * D; w = K + D; outp = t; oi = j; }
  else       { row = P + (size_t)(j - N) * D; w = K; outp = s; oi = j - N; }
  float4 r  = ((const float4*)row)[lane];
  float4 kk = ((const float4*)w)[lane];
  float acc = r.x * kk.x + r.y * kk.y + r.z * kk.z + r.w * kk.w;
  #pragma unroll
  for (int off = 32; off > 0; off >>= 1) acc += __shfl_down(acc, off, 64);
  if (lane == 0) outp[oi] = acc;
}

// --- 2) rank_n = #{m : t_m < t_n or (t_m==t_n and m<n)} — counting-sort rank.
__global__ __launch_bounds__(256) void k_rank_partial(
    const float* __restrict__ t, int* __restrict__ rank) {
  __shared__ float sm[256];
  int n = blockIdx.x * 256 + threadIdx.x;
  float tn = (n < N) ? t[n] : 0.f;
  int seglen = (N + RANK_SEGS - 1) / RANK_SEGS;
  int m0 = blockIdx.y * seglen;
  int m1 = min(N, m0 + seglen);
  int r = 0;
  for (int k0 = m0; k0 < m1; k0 += 256) {
    int m = k0 + threadIdx.x;
    sm[threadIdx.x] = (m < m1) ? t[m] : 0.f;
    __syncthreads();
    int lim = min(256, m1 - k0);
    for (int j = 0; j < lim; ++j) {
      float tm = sm[j];
      int mm = k0 + j;
      r += (tm < tn || (tm == tn && mm < n)) ? 1 : 0;
    }
    __syncthreads();
  }
  if (n < N && r) atomicAdd(&rank[n], r);
}

// --- 3) scatter into sorted order; precompute exp factors.
__global__ __launch_bounds__(256) void k_scatter(
    const float* __restrict__ t, const int* __restrict__ rank,
    float* __restrict__ tsort, float* __restrict__ eA, float* __restrict__ eC,
    int* __restrict__ idxs) {
  int n = blockIdx.x * 256 + threadIdx.x;
  if (n < N) {
    int r = rank[n];
    float tn = t[n];
    tsort[r] = tn;
    eA[r] = __expf(tn);
    eC[r] = __expf(ALPHA * tn);
    idxs[r] = n;
  }
}

// --- 4) per-chunk sums + atomic superchunk sums (SSA/SSC/ssa0/ssc0 pre-zeroed).
__global__ __launch_bounds__(256) void k_chunk_sums(
    const float* __restrict__ eA, const float* __restrict__ eC,
    const int* __restrict__ idxs, const float* __restrict__ V,
    float* __restrict__ SA, float* __restrict__ SC,
    float* __restrict__ sa0, float* __restrict__ sc0,
    float* __restrict__ SSA, float* __restrict__ SSC,
    float* __restrict__ ssa0, float* __restrict__ ssc0) {
  int g = blockIdx.x, d = threadIdx.x;
  int base = g * CS;
  float accA = 0.f, accC = 0.f, sa = 0.f, sc = 0.f;
  #pragma unroll
  for (int j = 0; j < CS; ++j) {
    int i = base + j;
    float ea = eA[i], ec = eC[i];
    float v = V[(size_t)idxs[i] * D + d];
    accA += ea * v; accC += ec * v;
    sa += ea; sc += ec;
  }
  SA[(size_t)g * D + d] = accA;
  SC[(size_t)g * D + d] = accC;
  int gs = g / SCHUNK;
  atomicAdd(&SSA[(size_t)gs * D + d], accA);
  atomicAdd(&SSC[(size_t)gs * D + d], accC);
  if (d == 0) {
    sa0[g] = sa; sc0[g] = sc;
    atomicAdd(&ssa0[gs], sa);
    atomicAdd(&ssc0[gs], sc);
  }
}

// --- 5) exclusive scan over 25 superchunks. 1 block; loads register-unrolled
// (all 25 independent -> one latency), then register scan + 26 row stores.
__global__ __launch_bounds__(256) void k_super_scan(
    const float* __restrict__ SSA, const float* __restrict__ SSC,
    const float* __restrict__ ssa0, const float* __restrict__ ssc0,
    float* __restrict__ PSA, float* __restrict__ PSC,
    float* __restrict__ Psa0, float* __restrict__ Psc0) {
  int d = threadIdx.x;
  float vA[NSUPER], vC[NSUPER];
  #pragma unroll
  for (int g = 0; g < NSUPER; ++g) {
    vA[g] = SSA[(size_t)g * D + d];
    vC[g] = SSC[(size_t)g * D + d];
  }
  float aA = 0.f, aC = 0.f;
  #pragma unroll
  for (int g = 0; g < NSUPER; ++g) {
    PSA[(size_t)g * D + d] = aA;
    PSC[(size_t)g * D + d] = aC;
    aA += vA[g]; aC += vC[g];
  }
  PSA[(size_t)NSUPER * D + d] = aA;
  PSC[(size_t)NSUPER * D + d] = aC;
  if (d == 0) {
    float a[NSUPER], c[NSUPER];
    #pragma unroll
    for (int g = 0; g < NSUPER; ++g) { a[g] = ssa0[g]; c[g] = ssc0[g]; }
    float s1 = 0.f, s2 = 0.f;
    #pragma unroll
    for (int g = 0; g < NSUPER; ++g) {
      Psa0[g] = s1; Psc0[g] = s2;
      s1 += a[g]; s2 += c[g];
    }
    Psa0[NSUPER] = s1; Psc0[NSUPER] = s2;
  }
}

// --- 6) per-patient: binary search k_b; prefix = superchunk row + <=24 chunk
// rows + <=15 gathered V rows; fused epilogue.
__global__ __launch_bounds__(256) void k_finalize(
    const float* __restrict__ P, const float* __restrict__ s,
    const float* __restrict__ tsort,
    const float* __restrict__ eA, const float* __restrict__ eC,
    const int* __restrict__ idxs, const float* __restrict__ V,
    const float* __restrict__ SA, const float* __restrict__ SC,
    const float* __restrict__ sa0, const float* __restrict__ sc0,
    const float* __restrict__ PSA, const float* __restrict__ PSC,
    const float* __restrict__ Psa0, const float* __restrict__ Psc0,
    float* __restrict__ out) {
  int b = blockIdx.x, d = threadIdx.x;
  float sb = s[b];
  float key = -sb;
  int lo = 0, hi = N;   // lower_bound: first idx with tsort[idx] >= key
  while (lo < hi) {
    int mid = (lo + hi) >> 1;
    if (tsort[mid] < key) lo = mid + 1; else hi = mid;
  }
  int k = lo;           // [0,k) alpha-branch, [k,N) plain branch
  int g = k >> 4;       // chunk index (CS=16); k==N -> g==G
  int gs = g / SCHUNK;  // superchunk index; g==G -> gs==NSUPER (total row)
  float prefA = PSA[(size_t)gs * D + d];
  float prefC = PSC[(size_t)gs * D + d];
  float pa = Psa0[gs], pc = Psc0[gs];
  for (int j = gs * SCHUNK; j < g; ++j) {
    prefA += SA[(size_t)j * D + d];
    prefC += SC[(size_t)j * D + d];
    pa += sa0[j]; pc += sc0[j];
  }
  for (int i = g << 4; i < k; ++i) {
    float ea = eA[i], ec = eC[i];
    float v = V[(size_t)idxs[i] * D + d];
    prefA += ea * v; prefC += ec * v;
    pa += ea; pc += ec;
  }
  float totA = PSA[(size_t)NSUPER * D + d];
  float ta0 = Psa0[NSUPER];
  float ea = __expf(sb), ec = __expf(ALPHA * sb);
  float l = ea * (ta0 - pa) + ec * pc;
  float agg = (ea * (totA - prefA) + ec * prefC) / l;
  out[(size_t)b * D + d] = P[(size_t)b * D + d] + agg;
}

extern "C" void kernel_launch(void* const* d_in, const int* in_sizes, int n_in,
                              void* d_out, int out_size, void* d_ws, size_t ws_size,
                              hipStream_t stream) {
  const float* P = (const float*)d_in[0];   // (B, D)
  const float* V = (const float*)d_in[1];   // (N, D)
  const float* K = (const float*)d_in[2];   // (2D, 1)
  float* out = (float*)d_out;

  char* w = (char*)d_ws;
  // --- zeroed region (single memset): rank + superchunk accumulators ---
  int*   rank  = (int*)w;   w += sizeof(int) * N;
  float* SSA   = (float*)w; w += sizeof(float) * (size_t)NSUPER * D;
  float* SSC   = (float*)w; w += sizeof(float) * (size_t)NSUPER * D;
  float* ssa0  = (float*)w; w += sizeof(float) * NSUPER;
  float* ssc0  = (float*)w; w += sizeof(float) * NSUPER;
  size_t zero_bytes = (size_t)(w - (char*)d_ws);
  // --- rest ---
  float* t     = (float*)w; w += sizeof(float) * N;
  float* s     = (float*)w; w += sizeof(float) * B;
  float* tsort = (float*)w; w += sizeof(float) * N;
  float* eA    = (float*)w; w += sizeof(float) * N;
  float* eC    = (float*)w; w += sizeof(float) * N;
  int*   idxs  = (int*)w;   w += sizeof(int) * N;
  float* SA    = (float*)w; w += sizeof(float) * (size_t)G * D;
  float* SC    = (float*)w; w += sizeof(float) * (size_t)G * D;
  float* sa0   = (float*)w; w += sizeof(float) * G;
  float* sc0   = (float*)w; w += sizeof(float) * G;
  float* PSA   = (float*)w; w += sizeof(float) * (size_t)(NSUPER + 1) * D;
  float* PSC   = (float*)w; w += sizeof(float) * (size_t)(NSUPER + 1) * D;
  float* Psa0  = (float*)w; w += sizeof(float) * (NSUPER + 1);
  float* Psc0  = (float*)w; w += sizeof(float) * (NSUPER + 1);
  // total ~1.8 MB of ws

  hipMemsetAsync(d_ws, 0, zero_bytes, stream);
  k_dot_scores<<<(N + B + 3) / 4, 256, 0, stream>>>(P, V, K, t, s);
  dim3 rg((N + 255) / 256, RANK_SEGS);
  k_rank_partial<<<rg, 256, 0, stream>>>(t, rank);
  k_scatter<<<(N + 255) / 256, 256, 0, stream>>>(t, rank, tsort, eA, eC, idxs);
  k_chunk_sums<<<G, 256, 0, stream>>>(eA, eC, idxs, V, SA, SC, sa0, sc0,
                                      SSA, SSC, ssa0, ssc0);
  k_super_scan<<<1, 256, 0, stream>>>(SSA, SSC, ssa0, ssc0, PSA, PSC, Psa0, Psc0);
  k_finalize<<<B, 256, 0, stream>>>(P, s, tsort, eA, eC, idxs, V,
                                    SA, SC, sa0, sc0, PSA, PSC, Psa0, Psc0, out);
}